// Round 6
// baseline (188.278 us; speedup 1.0000x reference)
//
#include <hip/hip_runtime.h>
#include <hip/hip_bf16.h>
#include <stdint.h>

typedef __bf16 bf16;
typedef __bf16 bf16x4 __attribute__((ext_vector_type(4)));
typedef __bf16 bf16x8 __attribute__((ext_vector_type(8)));
typedef float  f32x4  __attribute__((ext_vector_type(4)));
typedef float  f32x16 __attribute__((ext_vector_type(16)));

#define MFMA16(A_, B_, C_) __builtin_amdgcn_mfma_f32_16x16x32_bf16((A_), (B_), (C_), 0, 0, 0)
#define MFMA32(A_, B_, C_) __builtin_amdgcn_mfma_f32_32x32x16_bf16((A_), (B_), (C_), 0, 0, 0)

#define QSCALE 0.1803368801111137f  // 0.125 * log2(e), folded into Wq/bq

__device__ __forceinline__ void gload_lds16(const void* g, void* l) {
  __builtin_amdgcn_global_load_lds(
      (const __attribute__((address_space(1))) unsigned int*)g,
      (__attribute__((address_space(3))) unsigned int*)l, 16, 0, 0);
}

__device__ __forceinline__ unsigned pk2(float lo, float hi_) {
  union { bf16 h[2]; unsigned u; } t;
  t.h[0] = (bf16)lo; t.h[1] = (bf16)hi_;
  return t.u;
}

__device__ __forceinline__ float fast_exp2(float x) {
#if __has_builtin(__builtin_amdgcn_exp2f)
  return __builtin_amdgcn_exp2f(x);
#else
  return exp2f(x);
#endif
}

// ---------------------------------------------------------------------------
// prep: all weight transposes (fp32->bf16, out[n][k]=in[k][n]*scale) + bias pack
// ---------------------------------------------------------------------------
__global__ __launch_bounds__(256) void prep(const float* __restrict__ Wq,
                                            const float* __restrict__ Wk,
                                            const float* __restrict__ Wv,
                                            const float* __restrict__ Wo,
                                            const float* __restrict__ W1,
                                            const float* __restrict__ W2,
                                            const float* __restrict__ bq,
                                            const float* __restrict__ bk,
                                            const float* __restrict__ bv,
                                            bf16* __restrict__ wqkvT, bf16* __restrict__ woT,
                                            bf16* __restrict__ w1T, bf16* __restrict__ w2T,
                                            float* __restrict__ bqkv) {
  const int b = blockIdx.x;
  if (b >= 768) {
    int i = (b - 768) * 256 + threadIdx.x;
    if (i < 1536)
      bqkv[i] = (i < 512) ? bq[i] * QSCALE : (i < 1024 ? bk[i - 512] : bv[i - 1024]);
    return;
  }
  const float* in; bf16* outp; int K, N, t; float sc = 1.f;
  if (b < 64)       { in = Wq; outp = wqkvT;              K = 512;  N = 512;  t = b;       sc = QSCALE; }
  else if (b < 128) { in = Wk; outp = wqkvT + 512 * 512;  K = 512;  N = 512;  t = b - 64;  }
  else if (b < 192) { in = Wv; outp = wqkvT + 1024 * 512; K = 512;  N = 512;  t = b - 128; }
  else if (b < 256) { in = Wo; outp = woT;                K = 512;  N = 512;  t = b - 192; }
  else if (b < 512) { in = W1; outp = w1T;                K = 512;  N = 2048; t = b - 256; }
  else              { in = W2; outp = w2T;                K = 2048; N = 512;  t = b - 512; }
  const int tx = K >> 6;
  const int k0 = (t % tx) * 64, n0 = (t / tx) * 64;
  __shared__ bf16 tile[64][72];
  const int tid = threadIdx.x;
#pragma unroll
  for (int s = 0; s < 16; ++s) {
    int j = tid + s * 256;
    int r = j >> 6, c = j & 63;
    tile[r][c] = (bf16)(in[(size_t)(k0 + r) * N + n0 + c] * sc);
  }
  __syncthreads();
#pragma unroll
  for (int s = 0; s < 16; ++s) {
    int j = tid + s * 256;
    int n = j >> 6, k = j & 63;
    outp[(size_t)(n0 + n) * K + k0 + k] = tile[k][n];
  }
}

// ---------------------------------------------------------------------------
// LayerNorm: x fp32 [4096][512] -> out bf16. One wave per row.
// ---------------------------------------------------------------------------
__global__ __launch_bounds__(256) void ln_k(const float* __restrict__ x,
                                            const float* __restrict__ sc,
                                            const float* __restrict__ bi,
                                            bf16* __restrict__ out) {
  const int w = threadIdx.x >> 6, l = threadIdx.x & 63;
  const int row = blockIdx.x * 4 + w;
  const float4* xp = (const float4*)(x + (size_t)row * 512 + l * 8);
  float4 v0 = xp[0], v1 = xp[1];
  float xv[8] = {v0.x, v0.y, v0.z, v0.w, v1.x, v1.y, v1.z, v1.w};
  float s = 0.f, q = 0.f;
#pragma unroll
  for (int j = 0; j < 8; ++j) { s += xv[j]; q += xv[j] * xv[j]; }
#pragma unroll
  for (int m = 1; m < 64; m <<= 1) { s += __shfl_xor(s, m); q += __shfl_xor(q, m); }
  const float mean = s * (1.f / 512.f);
  const float var = q * (1.f / 512.f) - mean * mean;
  const float rstd = rsqrtf(var + 1e-6f);
  const float4* scp = (const float4*)(sc + l * 8);
  const float4* bip = (const float4*)(bi + l * 8);
  float4 s0 = scp[0], s1 = scp[1], b0 = bip[0], b1 = bip[1];
  float sv[8] = {s0.x, s0.y, s0.z, s0.w, s1.x, s1.y, s1.z, s1.w};
  float bv[8] = {b0.x, b0.y, b0.z, b0.w, b1.x, b1.y, b1.z, b1.w};
  bf16x8 ov;
#pragma unroll
  for (int j = 0; j < 8; ++j) ov[j] = (bf16)((xv[j] - mean) * rstd * sv[j] + bv[j]);
  *(bf16x8*)(out + (size_t)row * 512 + l * 8) = ov;
}

// ---------------------------------------------------------------------------
// ln2_comb: x2 = p0+p1+bo+x (fp32), h2 = LN(x2) (bf16)
// ---------------------------------------------------------------------------
__global__ __launch_bounds__(256) void ln2_comb(const float* __restrict__ p0,
                                                const float* __restrict__ p1,
                                                const float* __restrict__ x,
                                                const float* __restrict__ bo,
                                                const float* __restrict__ sc,
                                                const float* __restrict__ bi,
                                                float* __restrict__ x2,
                                                bf16* __restrict__ h2) {
  const int w = threadIdx.x >> 6, l = threadIdx.x & 63;
  const int row = blockIdx.x * 4 + w;
  const size_t base = (size_t)row * 512 + l * 8;
  float xv[8];
#pragma unroll
  for (int j = 0; j < 2; ++j) {
    float4 a = *(const float4*)(p0 + base + j * 4);
    float4 b = *(const float4*)(p1 + base + j * 4);
    float4 c = *(const float4*)(x + base + j * 4);
    float4 d = *(const float4*)(bo + l * 8 + j * 4);
    xv[j * 4 + 0] = a.x + b.x + c.x + d.x;
    xv[j * 4 + 1] = a.y + b.y + c.y + d.y;
    xv[j * 4 + 2] = a.z + b.z + c.z + d.z;
    xv[j * 4 + 3] = a.w + b.w + c.w + d.w;
  }
  *(float4*)(x2 + base) = make_float4(xv[0], xv[1], xv[2], xv[3]);
  *(float4*)(x2 + base + 4) = make_float4(xv[4], xv[5], xv[6], xv[7]);
  float s = 0.f, q = 0.f;
#pragma unroll
  for (int j = 0; j < 8; ++j) { s += xv[j]; q += xv[j] * xv[j]; }
#pragma unroll
  for (int m = 1; m < 64; m <<= 1) { s += __shfl_xor(s, m); q += __shfl_xor(q, m); }
  const float mean = s * (1.f / 512.f);
  const float var = q * (1.f / 512.f) - mean * mean;
  const float rstd = rsqrtf(var + 1e-6f);
  const float4* scp = (const float4*)(sc + l * 8);
  const float4* bip = (const float4*)(bi + l * 8);
  float4 s0 = scp[0], s1 = scp[1], b0 = bip[0], b1 = bip[1];
  float sv[8] = {s0.x, s0.y, s0.z, s0.w, s1.x, s1.y, s1.z, s1.w};
  float bv[8] = {b0.x, b0.y, b0.z, b0.w, b1.x, b1.y, b1.z, b1.w};
  bf16x8 ov;
#pragma unroll
  for (int j = 0; j < 8; ++j) ov[j] = (bf16)((xv[j] - mean) * rstd * sv[j] + bv[j]);
  *(bf16x8*)(h2 + base) = ov;
}

// out = sum(parts) + b2 + x2   (all fp32)
__global__ __launch_bounds__(256) void final_comb(const float* __restrict__ parts, int nsplit,
                                                  const float* __restrict__ b2,
                                                  const float* __restrict__ x2,
                                                  float* __restrict__ outp) {
  const int i4 = blockIdx.x * 256 + threadIdx.x;
  const size_t off = (size_t)i4 * 4;
  float4 acc = *(const float4*)(x2 + off);
  float4 bb = *(const float4*)(b2 + (off & 511));
  acc.x += bb.x; acc.y += bb.y; acc.z += bb.z; acc.w += bb.w;
  for (int z = 0; z < nsplit; ++z) {
    float4 p = *(const float4*)(parts + (size_t)z * 4096 * 512 + off);
    acc.x += p.x; acc.y += p.y; acc.z += p.z; acc.w += p.w;
  }
  *(float4*)(outp + off) = acc;
}

// ---------------------------------------------------------------------------
// GEMM core, BK=64, XOR-swizzled LDS.
// ---------------------------------------------------------------------------
template <int EPI>
__global__ __launch_bounds__(256) void gemm_bt(const bf16* __restrict__ A,
                                               const bf16* __restrict__ Bt,
                                               const float* __restrict__ bias,
                                               const float* __restrict__ res,
                                               void* __restrict__ outp,
                                               int M, int N, int K) {
  __shared__ bf16 a_lds[128 * 64];
  __shared__ bf16 b_lds[128 * 64];
  const int m0 = blockIdx.x * 128, n0 = blockIdx.y * 128;
  const int tid = threadIdx.x, l = tid & 63, w = tid >> 6;
  const int wm = w >> 1, wn = w & 1;
  const int lc = l & 15, g = l >> 4;
  const int srow = l >> 3;
  const int cs = (l & 7) ^ srow;

  f32x4 acc[4][4] = {};
  const int kiters = K >> 6;
  for (int kt = 0; kt < kiters; ++kt) {
    const int k0 = kt << 6;
#pragma unroll
    for (int r = 0; r < 4; ++r) {
      const int rg = r * 32 + w * 8;
      gload_lds16(A + (size_t)(m0 + rg + srow) * K + k0 + cs * 8,
                  (char*)a_lds + rg * 128);
      gload_lds16(Bt + (size_t)(n0 + rg + srow) * K + k0 + cs * 8,
                  (char*)b_lds + rg * 128);
    }
    __syncthreads();
#pragma unroll
    for (int kk = 0; kk < 2; ++kk) {
      bf16x8 af[4], bfr[4];
#pragma unroll
      for (int i = 0; i < 4; ++i) {
        const int sw = ((kk * 4 + g) ^ (lc & 7)) * 8;
        af[i]  = *(const bf16x8*)(a_lds + (wm * 64 + i * 16 + lc) * 64 + sw);
        bfr[i] = *(const bf16x8*)(b_lds + (wn * 64 + i * 16 + lc) * 64 + sw);
      }
#pragma unroll
      for (int mi = 0; mi < 4; ++mi)
#pragma unroll
        for (int ni = 0; ni < 4; ++ni)
          acc[mi][ni] = MFMA16(af[mi], bfr[ni], acc[mi][ni]);
    }
    __syncthreads();
  }

#pragma unroll
  for (int mi = 0; mi < 4; ++mi)
#pragma unroll
    for (int ni = 0; ni < 4; ++ni) {
      const int col = n0 + wn * 64 + ni * 16 + lc;
      const float bb = bias[col];
#pragma unroll
      for (int i = 0; i < 4; ++i) {
        const int row = m0 + wm * 64 + mi * 16 + g * 4 + i;
        float v = acc[mi][ni][i] + bb;
        if constexpr (EPI == 0) {
          ((bf16*)outp)[(size_t)row * N + col] = (bf16)v;
        } else if constexpr (EPI == 1) {
          ((float*)outp)[(size_t)row * N + col] = v + res[(size_t)row * N + col];
        } else {
          float t = -2.3022077697f * (v + 0.044715f * v * v * v);
          float gl = v / (1.f + fast_exp2(t));
          ((bf16*)outp)[(size_t)row * N + col] = (bf16)gl;
        }
      }
    }
}

// ---------------------------------------------------------------------------
// Split-K GEMM partial (BK=64, swizzled): parts[kz][M][N] raw f32
// ---------------------------------------------------------------------------
__global__ __launch_bounds__(256) void gemm_skp(const bf16* __restrict__ A,
                                                const bf16* __restrict__ Bt,
                                                float* __restrict__ parts,
                                                int M, int N, int Kstride, int Kc) {
  __shared__ bf16 a_lds[128 * 64];
  __shared__ bf16 b_lds[128 * 64];
  const int m0 = blockIdx.x * 128, n0 = blockIdx.y * 128, kz = blockIdx.z;
  A += (size_t)kz * Kc;
  Bt += (size_t)kz * Kc;
  float* outp = parts + (size_t)kz * M * N;
  const int tid = threadIdx.x, l = tid & 63, w = tid >> 6;
  const int wm = w >> 1, wn = w & 1;
  const int lc = l & 15, g = l >> 4;
  const int srow = l >> 3;
  const int cs = (l & 7) ^ srow;

  f32x4 acc[4][4] = {};
  const int kiters = Kc >> 6;
  for (int kt = 0; kt < kiters; ++kt) {
    const int k0 = kt << 6;
#pragma unroll
    for (int r = 0; r < 4; ++r) {
      const int rg = r * 32 + w * 8;
      gload_lds16(A + (size_t)(m0 + rg + srow) * Kstride + k0 + cs * 8,
                  (char*)a_lds + rg * 128);
      gload_lds16(Bt + (size_t)(n0 + rg + srow) * Kstride + k0 + cs * 8,
                  (char*)b_lds + rg * 128);
    }
    __syncthreads();
#pragma unroll
    for (int kk = 0; kk < 2; ++kk) {
      bf16x8 af[4], bfr[4];
#pragma unroll
      for (int i = 0; i < 4; ++i) {
        const int sw = ((kk * 4 + g) ^ (lc & 7)) * 8;
        af[i]  = *(const bf16x8*)(a_lds + (wm * 64 + i * 16 + lc) * 64 + sw);
        bfr[i] = *(const bf16x8*)(b_lds + (wn * 64 + i * 16 + lc) * 64 + sw);
      }
#pragma unroll
      for (int mi = 0; mi < 4; ++mi)
#pragma unroll
        for (int ni = 0; ni < 4; ++ni)
          acc[mi][ni] = MFMA16(af[mi], bfr[ni], acc[mi][ni]);
    }
    __syncthreads();
  }

#pragma unroll
  for (int mi = 0; mi < 4; ++mi)
#pragma unroll
    for (int ni = 0; ni < 4; ++ni) {
      const int col = n0 + wn * 64 + ni * 16 + lc;
#pragma unroll
      for (int i = 0; i < 4; ++i) {
        const int row = m0 + wm * 64 + mi * 16 + g * 4 + i;
        outp[(size_t)row * N + col] = acc[mi][ni][i];
      }
    }
}

// ---------------------------------------------------------------------------
// repack: K -> k2[h][t][64] (dense 128B rows); V -> v2[h][p][d][32] panels
// (panel p = key/32, 64B rows, coalesced for direct L2 fragment loads)
// ---------------------------------------------------------------------------
__global__ __launch_bounds__(256) void repack(const bf16* __restrict__ qkv,
                                              bf16* __restrict__ k2,
                                              bf16* __restrict__ v2) {
  __shared__ bf16 tile[64][72];
  const int t0 = blockIdx.x * 64;
  const int head = blockIdx.y;
  const int tid = threadIdx.x;
#pragma unroll
  for (int s = 0; s < 16; ++s) {
    int j = tid + s * 256;
    int t = j >> 6, d = j & 63;
    k2[(size_t)head * 262144 + (size_t)(t0 + t) * 64 + d] =
        qkv[(size_t)(t0 + t) * 1536 + 512 + head * 64 + d];
  }
#pragma unroll
  for (int s = 0; s < 16; ++s) {
    int j = tid + s * 256;
    int t = j >> 6, c = j & 63;
    tile[t][c] = qkv[(size_t)(t0 + t) * 1536 + 1024 + head * 64 + c];
  }
  __syncthreads();
#pragma unroll
  for (int s = 0; s < 16; ++s) {
    int j = tid + s * 256;
    int d = j >> 6, t = j & 63;
    v2[(size_t)head * 262144 + (size_t)((t0 >> 5) + (t >> 5)) * 2048 + d * 32 + (t & 31)] =
        tile[t][d];
  }
}

// ---------------------------------------------------------------------------
// Flash attention v6: NO LDS in main loop — K/V fragments loaded DIRECTLY
// from L2 (per-head K+V = 1MB, L2-resident, head pinned per XCD).
// 32x32x16 swapped-operand MFMA, in-register constant-max softmax
// (scale pre-folded into Wq/bq). Grid 1024 = ks(2) x qt(64) x head(8),
// 4 blocks/CU (launch_bounds(256,4), VGPR<=128), 16 waves/CU.
// Wave w: q-half (w&1), key-quarter 1024 keys (ks, w>>1) in 32 tiles of 32.
// Raw O partials (bf16) + l partials (f32); attn_comb divides (exact under
// constant-max softmax). Pair-combine via 17KB LDS at the end.
// ---------------------------------------------------------------------------
__global__ __launch_bounds__(256, 4) void attn_k(const bf16* __restrict__ qkv,
                                                 const bf16* __restrict__ k2,
                                                 const bf16* __restrict__ v2,
                                                 bf16* __restrict__ opart,
                                                 float* __restrict__ lpart) {
  const int bid = blockIdx.x;
  const int head = bid & 7;          // one head per XCD (L2 locality)
  const int qt = (bid >> 3) & 63;
  const int ks = bid >> 9;
  const int w = threadIdx.x >> 6, l = threadIdx.x & 63;
  const int hi = l >> 5, l5 = l & 31;
  const int pair = w >> 1, wq = w & 1;

  __shared__ float comb[2 * 64 * 33];   // 16896 B

  const bf16* kg = k2 + (size_t)head * 262144;
  const bf16* vg = v2 + (size_t)head * 262144;

  // Q fragments (Wq pre-scaled): qf[cc] = Q[q=l5][cc*16 + hi*8 + 0..7]
  const int qrow0 = qt * 64 + wq * 32;
  const bf16* qb = qkv + (size_t)(qrow0 + l5) * 1536 + head * 64;
  bf16x8 qf[4];
#pragma unroll
  for (int cc = 0; cc < 4; ++cc) qf[cc] = *(const bf16x8*)(qb + cc * 16 + hi * 8);

  const int kstart = ks * 2048 + pair * 1024;

  f32x16 o0 = {}, o1 = {};
  float psum = 0.f;

#pragma unroll 2
  for (int t = 0; t < 32; ++t) {
    const int kv0 = kstart + t * 32;
    const bf16* kb = kg + (size_t)kv0 * 64 + l5 * 64 + hi * 8;
    const bf16* vp = vg + (size_t)(kv0 >> 5) * 2048;
    bf16x8 kf0 = *(const bf16x8*)(kb);
    bf16x8 kf1 = *(const bf16x8*)(kb + 16);
    bf16x8 kf2 = *(const bf16x8*)(kb + 32);
    bf16x8 kf3 = *(const bf16x8*)(kb + 48);
    __builtin_amdgcn_s_setprio(1);
    f32x16 s = {};
    s = MFMA32(kf0, qf[0], s);
    s = MFMA32(kf1, qf[1], s);
    s = MFMA32(kf2, qf[2], s);
    s = MFMA32(kf3, qf[3], s);
    __builtin_amdgcn_s_setprio(0);

#pragma unroll
    for (int c = 0; c < 2; ++c) {
      bf16x8 vf0 = *(const bf16x8*)(vp + l5 * 32 + c * 16 + hi * 8);
      bf16x8 vf1 = *(const bf16x8*)(vp + (32 + l5) * 32 + c * 16 + hi * 8);
      float p[8];
#pragma unroll
      for (int j = 0; j < 8; ++j) p[j] = fast_exp2(s[c * 8 + j]);
      psum += ((p[0] + p[1]) + (p[2] + p[3])) + ((p[4] + p[5]) + (p[6] + p[7]));
      unsigned X = pk2(p[0], p[1]), X2 = pk2(p[2], p[3]);
      unsigned Y = pk2(p[4], p[5]), Y2 = pk2(p[6], p[7]);
      asm volatile("v_permlane32_swap_b32 %0, %1" : "+v"(X), "+v"(Y));
      asm volatile("v_permlane32_swap_b32 %0, %1" : "+v"(X2), "+v"(Y2));
      union { unsigned wd[4]; bf16x8 v; } pa;
      pa.wd[0] = X; pa.wd[1] = X2; pa.wd[2] = Y; pa.wd[3] = Y2;
      __builtin_amdgcn_s_setprio(1);
      o0 = MFMA32(vf0, pa.v, o0);
      o1 = MFMA32(vf1, pa.v, o1);
      __builtin_amdgcn_s_setprio(0);
    }
  }

  // combine the two pair (key-range) partials via LDS
  if (w >= 2) {
    float* cb = comb + ((w - 2) * 64 + l) * 33;
#pragma unroll
    for (int r = 0; r < 16; ++r) { cb[r] = o0[r]; cb[16 + r] = o1[r]; }
    cb[32] = psum;
  }
  __syncthreads();
  if (w < 2) {
    const float* cb = comb + (w * 64 + l) * 33;
#pragma unroll
    for (int r = 0; r < 16; ++r) { o0[r] += cb[r]; o1[r] += cb[16 + r]; }
    psum += cb[32];
    const float lsum = psum + __shfl_xor(psum, 32);
    bf16* ob = opart + (size_t)ks * 4096 * 512 + (size_t)(qrow0 + l5) * 512 + head * 64;
#pragma unroll
    for (int dt = 0; dt < 2; ++dt)
#pragma unroll
      for (int rg = 0; rg < 4; ++rg) {
        bf16x4 vv;
#pragma unroll
        for (int e = 0; e < 4; ++e) {
          const float ov = (dt == 0) ? o0[rg * 4 + e] : o1[rg * 4 + e];
          vv[e] = (bf16)ov;
        }
        *(bf16x4*)(ob + dt * 32 + rg * 8 + hi * 4) = vv;
      }
    if (hi == 0) lpart[(ks * 8 + head) * 4096 + qrow0 + l5] = lsum;
  }
}

// attnb[t][col] = (op0+op1)/(l0+l1)
__global__ __launch_bounds__(256) void attn_comb(const bf16* __restrict__ op,
                                                 const float* __restrict__ lp,
                                                 bf16* __restrict__ ob) {
  const int idx = blockIdx.x * 256 + threadIdx.x;   // 262144 = 4096 * 64
  const int t = idx >> 6, c8 = idx & 63;
  const int head = c8 >> 3;
  const size_t o = (size_t)t * 512 + c8 * 8;
  bf16x8 a = *(const bf16x8*)(op + o);
  bf16x8 b = *(const bf16x8*)(op + 2097152 + o);
  const float inv = 1.f / (lp[head * 4096 + t] + lp[32768 + head * 4096 + t]);
  bf16x8 r;
#pragma unroll
  for (int j = 0; j < 8; ++j) r[j] = (bf16)(((float)a[j] + (float)b[j]) * inv);
  *(bf16x8*)(ob + o) = r;
}

// ---------------------------------------------------------------------------
extern "C" void kernel_launch(void* const* d_in, const int* in_sizes, int n_in,
                              void* d_out, int out_size, void* d_ws, size_t ws_size,
                              hipStream_t stream) {
  const float* x    = (const float*)d_in[0];
  const float* ln1s = (const float*)d_in[1];
  const float* ln1b = (const float*)d_in[2];
  const float* Wq   = (const float*)d_in[3];
  const float* bq   = (const float*)d_in[4];
  const float* Wk   = (const float*)d_in[5];
  const float* bk   = (const float*)d_in[6];
  const float* Wv   = (const float*)d_in[7];
  const float* bv   = (const float*)d_in[8];
  const float* Wo   = (const float*)d_in[9];
  const float* bo   = (const float*)d_in[10];
  const float* ln2s = (const float*)d_in[11];
  const float* ln2b = (const float*)d_in[12];
  const float* W1   = (const float*)d_in[13];
  const float* b1   = (const float*)d_in[14];
  const float* W2   = (const float*)d_in[15];
  const float* b2   = (const float*)d_in[16];
  float* out = (float*)d_out;

  char* ws = (char*)d_ws;
  bf16*  wqkvT = (bf16*)(ws + 0);          // [1536][512] 1.5M
  bf16*  woT   = (bf16*)(ws + 1572864);    // [512][512]  0.5M
  bf16*  w1T   = (bf16*)(ws + 2097152);    // [2048][512] 2M
  bf16*  w2T   = (bf16*)(ws + 4194304);    // [512][2048] 2M
  float* bqkv  = (float*)(ws + 6291456);   // 6144 B
  float* lpart = (float*)(ws + 6297600);   // [2][8][4096] f32 = 256K -> 6559744
  bf16*  opart = (bf16*)(ws + 6559744);    // [2][4096][512] bf16 = 8M -> 14948352
  float* x2    = (float*)(ws + 6559744);   // overlays opart (disjoint lifetime)
  bf16*  h     = (bf16*)(ws + 14948352);   // 4M; shared by h / attnb / h2
  bf16*  qkv   = (bf16*)(ws + 19142656);   // [4096][1536] 12M -> 31725568
  bf16*  k2    = (bf16*)(ws + 31725568);   // [8][4096][64] 4M -> 35919872
  bf16*  v2    = (bf16*)(ws + 35919872);   // [8][128][64][32] 4M -> 40114176
  bf16*  attnb = h;
  bf16*  h2    = h;
  float* wop   = (float*)(ws + 19142656);  // 2x8M f32 over dead qkv+k2
  bf16*  gbuf  = qkv;                      // ffn1 out 16M over dead qkv+k2
  float* f2p   = (float*)(ws + 40114176);  // gated
  const size_t need4 = 40114176 + 4ull * 8388608;
  const size_t need2 = 40114176 + 2ull * 8388608;

  prep<<<774, 256, 0, stream>>>(Wq, Wk, Wv, Wo, W1, W2, bq, bk, bv,
                                wqkvT, woT, w1T, w2T, bqkv);

  ln_k<<<1024, 256, 0, stream>>>(x, ln1s, ln1b, h);
  gemm_bt<0><<<dim3(32, 12), 256, 0, stream>>>(h, wqkvT, bqkv, nullptr, qkv, 4096, 1536, 512);
  repack<<<dim3(64, 8), 256, 0, stream>>>(qkv, k2, v2);
  attn_k<<<1024, 256, 0, stream>>>(qkv, k2, v2, opart, lpart);
  attn_comb<<<1024, 256, 0, stream>>>(opart, lpart, attnb);
  gemm_skp<<<dim3(32, 4, 2), 256, 0, stream>>>(attnb, woT, wop, 4096, 512, 512, 256);
  ln2_comb<<<1024, 256, 0, stream>>>(wop, wop + 4096 * 512, x, bo, ln2s, ln2b, x2, h2);
  gemm_bt<2><<<dim3(32, 16), 256, 0, stream>>>(h2, w1T, b1, nullptr, gbuf, 4096, 2048, 512);
  if (ws_size >= need4) {
    gemm_skp<<<dim3(32, 4, 4), 256, 0, stream>>>(gbuf, w2T, f2p, 4096, 512, 2048, 512);
    final_comb<<<2048, 256, 0, stream>>>(f2p, 4, b2, x2, out);
  } else if (ws_size >= need2) {
    gemm_skp<<<dim3(32, 4, 2), 256, 0, stream>>>(gbuf, w2T, f2p, 4096, 512, 2048, 1024);
    final_comb<<<2048, 256, 0, stream>>>(f2p, 2, b2, x2, out);
  } else {
    gemm_bt<1><<<dim3(32, 4), 256, 0, stream>>>(gbuf, w2T, b2, x2, out, 4096, 512, 2048);
  }
}

// Round 7
// 148.701 us; speedup vs baseline: 1.2662x; 1.2662x over previous
//
#include <hip/hip_runtime.h>
#include <hip/hip_bf16.h>
#include <stdint.h>

typedef __bf16 bf16;
typedef __bf16 bf16x4 __attribute__((ext_vector_type(4)));
typedef __bf16 bf16x8 __attribute__((ext_vector_type(8)));
typedef float  f32x4  __attribute__((ext_vector_type(4)));
typedef float  f32x16 __attribute__((ext_vector_type(16)));

#define MFMA16(A_, B_, C_) __builtin_amdgcn_mfma_f32_16x16x32_bf16((A_), (B_), (C_), 0, 0, 0)
#define MFMA32(A_, B_, C_) __builtin_amdgcn_mfma_f32_32x32x16_bf16((A_), (B_), (C_), 0, 0, 0)

#define QSCALE 0.1803368801111137f  // 0.125 * log2(e), folded into Wq/bq

__device__ __forceinline__ void gload_lds16(const void* g, void* l) {
  __builtin_amdgcn_global_load_lds(
      (const __attribute__((address_space(1))) unsigned int*)g,
      (__attribute__((address_space(3))) unsigned int*)l, 16, 0, 0);
}

__device__ __forceinline__ unsigned pk2(float lo, float hi_) {
  union { bf16 h[2]; unsigned u; } t;
  t.h[0] = (bf16)lo; t.h[1] = (bf16)hi_;
  return t.u;
}

__device__ __forceinline__ float fast_exp2(float x) {
#if __has_builtin(__builtin_amdgcn_exp2f)
  return __builtin_amdgcn_exp2f(x);
#else
  return exp2f(x);
#endif
}

// ---------------------------------------------------------------------------
// prep: all weight transposes (fp32->bf16, out[n][k]=in[k][n]*scale) + bias pack
// ---------------------------------------------------------------------------
__global__ __launch_bounds__(256) void prep(const float* __restrict__ Wq,
                                            const float* __restrict__ Wk,
                                            const float* __restrict__ Wv,
                                            const float* __restrict__ Wo,
                                            const float* __restrict__ W1,
                                            const float* __restrict__ W2,
                                            const float* __restrict__ bq,
                                            const float* __restrict__ bk,
                                            const float* __restrict__ bv,
                                            bf16* __restrict__ wqkvT, bf16* __restrict__ woT,
                                            bf16* __restrict__ w1T, bf16* __restrict__ w2T,
                                            float* __restrict__ bqkv) {
  const int b = blockIdx.x;
  if (b >= 768) {
    int i = (b - 768) * 256 + threadIdx.x;
    if (i < 1536)
      bqkv[i] = (i < 512) ? bq[i] * QSCALE : (i < 1024 ? bk[i - 512] : bv[i - 1024]);
    return;
  }
  const float* in; bf16* outp; int K, N, t; float sc = 1.f;
  if (b < 64)       { in = Wq; outp = wqkvT;              K = 512;  N = 512;  t = b;       sc = QSCALE; }
  else if (b < 128) { in = Wk; outp = wqkvT + 512 * 512;  K = 512;  N = 512;  t = b - 64;  }
  else if (b < 192) { in = Wv; outp = wqkvT + 1024 * 512; K = 512;  N = 512;  t = b - 128; }
  else if (b < 256) { in = Wo; outp = woT;                K = 512;  N = 512;  t = b - 192; }
  else if (b < 512) { in = W1; outp = w1T;                K = 512;  N = 2048; t = b - 256; }
  else              { in = W2; outp = w2T;                K = 2048; N = 512;  t = b - 512; }
  const int tx = K >> 6;
  const int k0 = (t % tx) * 64, n0 = (t / tx) * 64;
  __shared__ bf16 tile[64][72];
  const int tid = threadIdx.x;
#pragma unroll
  for (int s = 0; s < 16; ++s) {
    int j = tid + s * 256;
    int r = j >> 6, c = j & 63;
    tile[r][c] = (bf16)(in[(size_t)(k0 + r) * N + n0 + c] * sc);
  }
  __syncthreads();
#pragma unroll
  for (int s = 0; s < 16; ++s) {
    int j = tid + s * 256;
    int n = j >> 6, k = j & 63;
    outp[(size_t)(n0 + n) * K + k0 + k] = tile[k][n];
  }
}

// ---------------------------------------------------------------------------
// LayerNorm: x fp32 [4096][512] -> out bf16. One wave per row.
// ---------------------------------------------------------------------------
__global__ __launch_bounds__(256) void ln_k(const float* __restrict__ x,
                                            const float* __restrict__ sc,
                                            const float* __restrict__ bi,
                                            bf16* __restrict__ out) {
  const int w = threadIdx.x >> 6, l = threadIdx.x & 63;
  const int row = blockIdx.x * 4 + w;
  const float4* xp = (const float4*)(x + (size_t)row * 512 + l * 8);
  float4 v0 = xp[0], v1 = xp[1];
  float xv[8] = {v0.x, v0.y, v0.z, v0.w, v1.x, v1.y, v1.z, v1.w};
  float s = 0.f, q = 0.f;
#pragma unroll
  for (int j = 0; j < 8; ++j) { s += xv[j]; q += xv[j] * xv[j]; }
#pragma unroll
  for (int m = 1; m < 64; m <<= 1) { s += __shfl_xor(s, m); q += __shfl_xor(q, m); }
  const float mean = s * (1.f / 512.f);
  const float var = q * (1.f / 512.f) - mean * mean;
  const float rstd = rsqrtf(var + 1e-6f);
  const float4* scp = (const float4*)(sc + l * 8);
  const float4* bip = (const float4*)(bi + l * 8);
  float4 s0 = scp[0], s1 = scp[1], b0 = bip[0], b1 = bip[1];
  float sv[8] = {s0.x, s0.y, s0.z, s0.w, s1.x, s1.y, s1.z, s1.w};
  float bv[8] = {b0.x, b0.y, b0.z, b0.w, b1.x, b1.y, b1.z, b1.w};
  bf16x8 ov;
#pragma unroll
  for (int j = 0; j < 8; ++j) ov[j] = (bf16)((xv[j] - mean) * rstd * sv[j] + bv[j]);
  *(bf16x8*)(out + (size_t)row * 512 + l * 8) = ov;
}

// ---------------------------------------------------------------------------
// ln2_comb: x2 = p0+p1+bo+x (fp32), h2 = LN(x2) (bf16)
// ---------------------------------------------------------------------------
__global__ __launch_bounds__(256) void ln2_comb(const float* __restrict__ p0,
                                                const float* __restrict__ p1,
                                                const float* __restrict__ x,
                                                const float* __restrict__ bo,
                                                const float* __restrict__ sc,
                                                const float* __restrict__ bi,
                                                float* __restrict__ x2,
                                                bf16* __restrict__ h2) {
  const int w = threadIdx.x >> 6, l = threadIdx.x & 63;
  const int row = blockIdx.x * 4 + w;
  const size_t base = (size_t)row * 512 + l * 8;
  float xv[8];
#pragma unroll
  for (int j = 0; j < 2; ++j) {
    float4 a = *(const float4*)(p0 + base + j * 4);
    float4 b = *(const float4*)(p1 + base + j * 4);
    float4 c = *(const float4*)(x + base + j * 4);
    float4 d = *(const float4*)(bo + l * 8 + j * 4);
    xv[j * 4 + 0] = a.x + b.x + c.x + d.x;
    xv[j * 4 + 1] = a.y + b.y + c.y + d.y;
    xv[j * 4 + 2] = a.z + b.z + c.z + d.z;
    xv[j * 4 + 3] = a.w + b.w + c.w + d.w;
  }
  *(float4*)(x2 + base) = make_float4(xv[0], xv[1], xv[2], xv[3]);
  *(float4*)(x2 + base + 4) = make_float4(xv[4], xv[5], xv[6], xv[7]);
  float s = 0.f, q = 0.f;
#pragma unroll
  for (int j = 0; j < 8; ++j) { s += xv[j]; q += xv[j] * xv[j]; }
#pragma unroll
  for (int m = 1; m < 64; m <<= 1) { s += __shfl_xor(s, m); q += __shfl_xor(q, m); }
  const float mean = s * (1.f / 512.f);
  const float var = q * (1.f / 512.f) - mean * mean;
  const float rstd = rsqrtf(var + 1e-6f);
  const float4* scp = (const float4*)(sc + l * 8);
  const float4* bip = (const float4*)(bi + l * 8);
  float4 s0 = scp[0], s1 = scp[1], b0 = bip[0], b1 = bip[1];
  float sv[8] = {s0.x, s0.y, s0.z, s0.w, s1.x, s1.y, s1.z, s1.w};
  float bv[8] = {b0.x, b0.y, b0.z, b0.w, b1.x, b1.y, b1.z, b1.w};
  bf16x8 ov;
#pragma unroll
  for (int j = 0; j < 8; ++j) ov[j] = (bf16)((xv[j] - mean) * rstd * sv[j] + bv[j]);
  *(bf16x8*)(h2 + base) = ov;
}

// out = sum(parts) + b2 + x2   (all fp32)
__global__ __launch_bounds__(256) void final_comb(const float* __restrict__ parts, int nsplit,
                                                  const float* __restrict__ b2,
                                                  const float* __restrict__ x2,
                                                  float* __restrict__ outp) {
  const int i4 = blockIdx.x * 256 + threadIdx.x;
  const size_t off = (size_t)i4 * 4;
  float4 acc = *(const float4*)(x2 + off);
  float4 bb = *(const float4*)(b2 + (off & 511));
  acc.x += bb.x; acc.y += bb.y; acc.z += bb.z; acc.w += bb.w;
  for (int z = 0; z < nsplit; ++z) {
    float4 p = *(const float4*)(parts + (size_t)z * 4096 * 512 + off);
    acc.x += p.x; acc.y += p.y; acc.z += p.z; acc.w += p.w;
  }
  *(float4*)(outp + off) = acc;
}

// ---------------------------------------------------------------------------
// GEMM core, BK=64, XOR-swizzled LDS.
// ---------------------------------------------------------------------------
template <int EPI>
__global__ __launch_bounds__(256) void gemm_bt(const bf16* __restrict__ A,
                                               const bf16* __restrict__ Bt,
                                               const float* __restrict__ bias,
                                               const float* __restrict__ res,
                                               void* __restrict__ outp,
                                               int M, int N, int K) {
  __shared__ bf16 a_lds[128 * 64];
  __shared__ bf16 b_lds[128 * 64];
  const int m0 = blockIdx.x * 128, n0 = blockIdx.y * 128;
  const int tid = threadIdx.x, l = tid & 63, w = tid >> 6;
  const int wm = w >> 1, wn = w & 1;
  const int lc = l & 15, g = l >> 4;
  const int srow = l >> 3;
  const int cs = (l & 7) ^ srow;

  f32x4 acc[4][4] = {};
  const int kiters = K >> 6;
  for (int kt = 0; kt < kiters; ++kt) {
    const int k0 = kt << 6;
#pragma unroll
    for (int r = 0; r < 4; ++r) {
      const int rg = r * 32 + w * 8;
      gload_lds16(A + (size_t)(m0 + rg + srow) * K + k0 + cs * 8,
                  (char*)a_lds + rg * 128);
      gload_lds16(Bt + (size_t)(n0 + rg + srow) * K + k0 + cs * 8,
                  (char*)b_lds + rg * 128);
    }
    __syncthreads();
#pragma unroll
    for (int kk = 0; kk < 2; ++kk) {
      bf16x8 af[4], bfr[4];
#pragma unroll
      for (int i = 0; i < 4; ++i) {
        const int sw = ((kk * 4 + g) ^ (lc & 7)) * 8;
        af[i]  = *(const bf16x8*)(a_lds + (wm * 64 + i * 16 + lc) * 64 + sw);
        bfr[i] = *(const bf16x8*)(b_lds + (wn * 64 + i * 16 + lc) * 64 + sw);
      }
#pragma unroll
      for (int mi = 0; mi < 4; ++mi)
#pragma unroll
        for (int ni = 0; ni < 4; ++ni)
          acc[mi][ni] = MFMA16(af[mi], bfr[ni], acc[mi][ni]);
    }
    __syncthreads();
  }

#pragma unroll
  for (int mi = 0; mi < 4; ++mi)
#pragma unroll
    for (int ni = 0; ni < 4; ++ni) {
      const int col = n0 + wn * 64 + ni * 16 + lc;
      const float bb = bias[col];
#pragma unroll
      for (int i = 0; i < 4; ++i) {
        const int row = m0 + wm * 64 + mi * 16 + g * 4 + i;
        float v = acc[mi][ni][i] + bb;
        if constexpr (EPI == 0) {
          ((bf16*)outp)[(size_t)row * N + col] = (bf16)v;
        } else if constexpr (EPI == 1) {
          ((float*)outp)[(size_t)row * N + col] = v + res[(size_t)row * N + col];
        } else {
          float t = -2.3022077697f * (v + 0.044715f * v * v * v);
          float gl = v / (1.f + fast_exp2(t));
          ((bf16*)outp)[(size_t)row * N + col] = (bf16)gl;
        }
      }
    }
}

// ---------------------------------------------------------------------------
// Split-K GEMM partial (BK=64, swizzled): parts[kz][M][N] raw f32
// ---------------------------------------------------------------------------
__global__ __launch_bounds__(256) void gemm_skp(const bf16* __restrict__ A,
                                                const bf16* __restrict__ Bt,
                                                float* __restrict__ parts,
                                                int M, int N, int Kstride, int Kc) {
  __shared__ bf16 a_lds[128 * 64];
  __shared__ bf16 b_lds[128 * 64];
  const int m0 = blockIdx.x * 128, n0 = blockIdx.y * 128, kz = blockIdx.z;
  A += (size_t)kz * Kc;
  Bt += (size_t)kz * Kc;
  float* outp = parts + (size_t)kz * M * N;
  const int tid = threadIdx.x, l = tid & 63, w = tid >> 6;
  const int wm = w >> 1, wn = w & 1;
  const int lc = l & 15, g = l >> 4;
  const int srow = l >> 3;
  const int cs = (l & 7) ^ srow;

  f32x4 acc[4][4] = {};
  const int kiters = Kc >> 6;
  for (int kt = 0; kt < kiters; ++kt) {
    const int k0 = kt << 6;
#pragma unroll
    for (int r = 0; r < 4; ++r) {
      const int rg = r * 32 + w * 8;
      gload_lds16(A + (size_t)(m0 + rg + srow) * Kstride + k0 + cs * 8,
                  (char*)a_lds + rg * 128);
      gload_lds16(Bt + (size_t)(n0 + rg + srow) * Kstride + k0 + cs * 8,
                  (char*)b_lds + rg * 128);
    }
    __syncthreads();
#pragma unroll
    for (int kk = 0; kk < 2; ++kk) {
      bf16x8 af[4], bfr[4];
#pragma unroll
      for (int i = 0; i < 4; ++i) {
        const int sw = ((kk * 4 + g) ^ (lc & 7)) * 8;
        af[i]  = *(const bf16x8*)(a_lds + (wm * 64 + i * 16 + lc) * 64 + sw);
        bfr[i] = *(const bf16x8*)(b_lds + (wn * 64 + i * 16 + lc) * 64 + sw);
      }
#pragma unroll
      for (int mi = 0; mi < 4; ++mi)
#pragma unroll
        for (int ni = 0; ni < 4; ++ni)
          acc[mi][ni] = MFMA16(af[mi], bfr[ni], acc[mi][ni]);
    }
    __syncthreads();
  }

#pragma unroll
  for (int mi = 0; mi < 4; ++mi)
#pragma unroll
    for (int ni = 0; ni < 4; ++ni) {
      const int col = n0 + wn * 64 + ni * 16 + lc;
#pragma unroll
      for (int i = 0; i < 4; ++i) {
        const int row = m0 + wm * 64 + mi * 16 + g * 4 + i;
        outp[(size_t)row * N + col] = acc[mi][ni][i];
      }
    }
}

// ---------------------------------------------------------------------------
// repack: K -> k2[h][t][64] (dense 128B rows); V -> v2[h][p][d][32] panels
// ---------------------------------------------------------------------------
__global__ __launch_bounds__(256) void repack(const bf16* __restrict__ qkv,
                                              bf16* __restrict__ k2,
                                              bf16* __restrict__ v2) {
  __shared__ bf16 tile[64][72];
  const int t0 = blockIdx.x * 64;
  const int head = blockIdx.y;
  const int tid = threadIdx.x;
#pragma unroll
  for (int s = 0; s < 16; ++s) {
    int j = tid + s * 256;
    int t = j >> 6, d = j & 63;
    k2[(size_t)head * 262144 + (size_t)(t0 + t) * 64 + d] =
        qkv[(size_t)(t0 + t) * 1536 + 512 + head * 64 + d];
  }
#pragma unroll
  for (int s = 0; s < 16; ++s) {
    int j = tid + s * 256;
    int t = j >> 6, c = j & 63;
    tile[t][c] = qkv[(size_t)(t0 + t) * 1536 + 1024 + head * 64 + c];
  }
  __syncthreads();
#pragma unroll
  for (int s = 0; s < 16; ++s) {
    int j = tid + s * 256;
    int d = j >> 6, t = j & 63;
    v2[(size_t)head * 262144 + (size_t)((t0 >> 5) + (t >> 5)) * 2048 + d * 32 + (t & 31)] =
        tile[t][d];
  }
}

// ---------------------------------------------------------------------------
// Flash attention v7: v4's block-shared LDS staging structure + lean math.
// Grid 1024 = ks(2) x qt(64) x head(8). 4 waves; pair=w>>1 owns a 1024-key
// range, wq=w&1 a 32-q-row half. LDS 32KB (4 blocks/CU): per pair,
// K dbuf [2][32 keys][128B] + paired-V dbuf [2][32 rows][128B]
// (V row r = Vt[d=r][32keys] ++ Vt[d=32+r][32keys]); both tiles use the
// SAME ^(row&7) chunk swizzle, staged from dense k2/v2 with loop-invariant
// per-lane source offsets advanced by +=4096B per tile (no per-tile muls).
// One barrier per tile (compiler drains vmcnt at barrier -> dbuf safe).
// Constant-max in-register softmax; raw v_exp2; permlane P pack.
// Raw O/l partials; attn_comb divides (exact).
// ---------------------------------------------------------------------------
__global__ __launch_bounds__(256, 4) void attn_k(const bf16* __restrict__ qkv,
                                                 const bf16* __restrict__ k2,
                                                 const bf16* __restrict__ v2,
                                                 bf16* __restrict__ opart,
                                                 float* __restrict__ lpart) {
  const int bid = blockIdx.x;
  const int head = bid & 7;          // one head per XCD (L2 locality)
  const int qt = (bid >> 3) & 63;
  const int ks = bid >> 9;
  const int w = threadIdx.x >> 6, l = threadIdx.x & 63;
  const int hi = l >> 5, l5 = l & 31;
  const int pair = w >> 1, wq = w & 1;

  __shared__ __align__(16) char smem[32768];
  char* kt_l = smem + pair * 16384;   // [2][4096] B
  char* vt_l = kt_l + 8192;           // [2][4096] B

  // Q fragments (Wq pre-scaled): qf[cc] = Q[q=l5][cc*16 + hi*8 + 0..7]
  const int qrow0 = qt * 64 + wq * 32;
  const bf16* qb = qkv + (size_t)(qrow0 + l5) * 1536 + head * 64;
  bf16x8 qf[4];
#pragma unroll
  for (int cc = 0; cc < 4; ++cc) qf[cc] = *(const bf16x8*)(qb + cc * 16 + hi * 8);

  const int kstart = ks * 2048 + pair * 1024;

  // loop-invariant staging source addresses (bytes); advance 4096/tile
  const int lr = l >> 3;             // phys row within 8-row group
  const int lc3 = (l & 7) ^ lr;      // logical chunk for phys chunk l&7 (f=row&7)
  const char* kg = (const char*)k2 + (size_t)head * 524288 + (size_t)kstart * 128 +
                   (wq * 16 + lr) * 128 + lc3 * 16;
  const char* vg = (const char*)v2 + (size_t)head * 524288 + (size_t)(kstart >> 5) * 4096 +
                   (lc3 >> 2) * 2048 + (wq * 16 + lr) * 64 + (lc3 & 3) * 16;
  const int kdst = wq * 2048;        // wave's LDS dest base (within buf)

#define STAGE(B_)                                                            \
  do {                                                                       \
    gload_lds16(kg,        kt_l + (B_) * 4096 + kdst);                       \
    gload_lds16(kg + 1024, kt_l + (B_) * 4096 + kdst + 1024);                \
    gload_lds16(vg,        vt_l + (B_) * 4096 + kdst);                       \
    gload_lds16(vg + 512,  vt_l + (B_) * 4096 + kdst + 1024);                \
    kg += 4096; vg += 4096;                                                  \
  } while (0)

  STAGE(0);
  __syncthreads();

  f32x16 o0 = {}, o1 = {};
  float psum = 0.f;
  const int swl = l5 & 7;
  const char* kbase = kt_l + l5 * 128;
  const char* vbase = vt_l + l5 * 128;

  for (int t = 0; t < 32; ++t) {
    const int cur = t & 1;
    if (t < 31) STAGE(cur ^ 1);

    __builtin_amdgcn_s_setprio(1);
    f32x16 s = {};
#pragma unroll
    for (int cc = 0; cc < 4; ++cc) {
      bf16x8 kf = *(const bf16x8*)(kbase + cur * 4096 + ((cc * 2 + hi) ^ swl) * 16);
      s = MFMA32(kf, qf[cc], s);
    }
    __builtin_amdgcn_s_setprio(0);

#pragma unroll
    for (int c = 0; c < 2; ++c) {
      float p[8];
#pragma unroll
      for (int j = 0; j < 8; ++j) p[j] = fast_exp2(s[c * 8 + j]);
      psum += ((p[0] + p[1]) + (p[2] + p[3])) + ((p[4] + p[5]) + (p[6] + p[7]));
      unsigned X = pk2(p[0], p[1]), X2 = pk2(p[2], p[3]);
      unsigned Y = pk2(p[4], p[5]), Y2 = pk2(p[6], p[7]);
      asm volatile("v_permlane32_swap_b32 %0, %1" : "+v"(X), "+v"(Y));
      asm volatile("v_permlane32_swap_b32 %0, %1" : "+v"(X2), "+v"(Y2));
      union { unsigned wd[4]; bf16x8 v; } pa;
      pa.wd[0] = X; pa.wd[1] = X2; pa.wd[2] = Y; pa.wd[3] = Y2;
      bf16x8 vf0 = *(const bf16x8*)(vbase + cur * 4096 + ((c * 2 + hi) ^ swl) * 16);
      bf16x8 vf1 = *(const bf16x8*)(vbase + cur * 4096 + ((4 + c * 2 + hi) ^ swl) * 16);
      __builtin_amdgcn_s_setprio(1);
      o0 = MFMA32(vf0, pa.v, o0);
      o1 = MFMA32(vf1, pa.v, o1);
      __builtin_amdgcn_s_setprio(0);
    }
    __syncthreads();   // drains staging vmcnt (compiler) + tile handoff
  }
#undef STAGE

  // combine the two pair (key-range) partials via LDS (tiles dead)
  float* comb = (float*)smem;   // 16896 B
  if (w >= 2) {
    float* cb = comb + ((w - 2) * 64 + l) * 33;
#pragma unroll
    for (int r = 0; r < 16; ++r) { cb[r] = o0[r]; cb[16 + r] = o1[r]; }
    cb[32] = psum;
  }
  __syncthreads();
  if (w < 2) {
    const float* cb = comb + (w * 64 + l) * 33;
#pragma unroll
    for (int r = 0; r < 16; ++r) { o0[r] += cb[r]; o1[r] += cb[16 + r]; }
    psum += cb[32];
    const float lsum = psum + __shfl_xor(psum, 32);
    bf16* ob = opart + (size_t)ks * 4096 * 512 + (size_t)(qrow0 + l5) * 512 + head * 64;
#pragma unroll
    for (int dt = 0; dt < 2; ++dt)
#pragma unroll
      for (int rg = 0; rg < 4; ++rg) {
        bf16x4 vv;
#pragma unroll
        for (int e = 0; e < 4; ++e) {
          const float ov = (dt == 0) ? o0[rg * 4 + e] : o1[rg * 4 + e];
          vv[e] = (bf16)ov;
        }
        *(bf16x4*)(ob + dt * 32 + rg * 8 + hi * 4) = vv;
      }
    if (hi == 0) lpart[(ks * 8 + head) * 4096 + qrow0 + l5] = lsum;
  }
}

// attnb[t][col] = (op0+op1)/(l0+l1)
__global__ __launch_bounds__(256) void attn_comb(const bf16* __restrict__ op,
                                                 const float* __restrict__ lp,
                                                 bf16* __restrict__ ob) {
  const int idx = blockIdx.x * 256 + threadIdx.x;   // 262144 = 4096 * 64
  const int t = idx >> 6, c8 = idx & 63;
  const int head = c8 >> 3;
  const size_t o = (size_t)t * 512 + c8 * 8;
  bf16x8 a = *(const bf16x8*)(op + o);
  bf16x8 b = *(const bf16x8*)(op + 2097152 + o);
  const float inv = 1.f / (lp[head * 4096 + t] + lp[32768 + head * 4096 + t]);
  bf16x8 r;
#pragma unroll
  for (int j = 0; j < 8; ++j) r[j] = (bf16)(((float)a[j] + (float)b[j]) * inv);
  *(bf16x8*)(ob + o) = r;
}

// ---------------------------------------------------------------------------
extern "C" void kernel_launch(void* const* d_in, const int* in_sizes, int n_in,
                              void* d_out, int out_size, void* d_ws, size_t ws_size,
                              hipStream_t stream) {
  const float* x    = (const float*)d_in[0];
  const float* ln1s = (const float*)d_in[1];
  const float* ln1b = (const float*)d_in[2];
  const float* Wq   = (const float*)d_in[3];
  const float* bq   = (const float*)d_in[4];
  const float* Wk   = (const float*)d_in[5];
  const float* bk   = (const float*)d_in[6];
  const float* Wv   = (const float*)d_in[7];
  const float* bv   = (const float*)d_in[8];
  const float* Wo   = (const float*)d_in[9];
  const float* bo   = (const float*)d_in[10];
  const float* ln2s = (const float*)d_in[11];
  const float* ln2b = (const float*)d_in[12];
  const float* W1   = (const float*)d_in[13];
  const float* b1   = (const float*)d_in[14];
  const float* W2   = (const float*)d_in[15];
  const float* b2   = (const float*)d_in[16];
  float* out = (float*)d_out;

  char* ws = (char*)d_ws;
  bf16*  wqkvT = (bf16*)(ws + 0);          // [1536][512] 1.5M
  bf16*  woT   = (bf16*)(ws + 1572864);    // [512][512]  0.5M
  bf16*  w1T   = (bf16*)(ws + 2097152);    // [2048][512] 2M
  bf16*  w2T   = (bf16*)(ws + 4194304);    // [512][2048] 2M
  float* bqkv  = (float*)(ws + 6291456);   // 6144 B
  float* lpart = (float*)(ws + 6297600);   // [2][8][4096] f32 = 256K -> 6559744
  bf16*  opart = (bf16*)(ws + 6559744);    // [2][4096][512] bf16 -> 14948352
  float* x2    = (float*)(ws + 6559744);   // overlays opart (disjoint lifetime)
  bf16*  h     = (bf16*)(ws + 14948352);   // 4M; shared by h / attnb / h2
  bf16*  qkv   = (bf16*)(ws + 19142656);   // [4096][1536] 12M -> 31725568
  bf16*  k2    = (bf16*)(ws + 31725568);   // [8][4096][64] 4M -> 35919872
  bf16*  v2    = (bf16*)(ws + 35919872);   // [8][128][64][32] 4M -> 40114176
  bf16*  attnb = h;
  bf16*  h2    = h;
  float* wop   = (float*)(ws + 19142656);  // 2x8M f32 over dead qkv+k2
  bf16*  gbuf  = qkv;                      // ffn1 out 16M over dead qkv+k2
  float* f2p   = (float*)(ws + 40114176);  // gated
  const size_t need4 = 40114176 + 4ull * 8388608;
  const size_t need2 = 40114176 + 2ull * 8388608;

  prep<<<774, 256, 0, stream>>>(Wq, Wk, Wv, Wo, W1, W2, bq, bk, bv,
                                wqkvT, woT, w1T, w2T, bqkv);

  ln_k<<<1024, 256, 0, stream>>>(x, ln1s, ln1b, h);
  gemm_bt<0><<<dim3(32, 12), 256, 0, stream>>>(h, wqkvT, bqkv, nullptr, qkv, 4096, 1536, 512);
  repack<<<dim3(64, 8), 256, 0, stream>>>(qkv, k2, v2);
  attn_k<<<1024, 256, 0, stream>>>(qkv, k2, v2, opart, lpart);
  attn_comb<<<1024, 256, 0, stream>>>(opart, lpart, attnb);
  gemm_skp<<<dim3(32, 4, 2), 256, 0, stream>>>(attnb, woT, wop, 4096, 512, 512, 256);
  ln2_comb<<<1024, 256, 0, stream>>>(wop, wop + 4096 * 512, x, bo, ln2s, ln2b, x2, h2);
  gemm_bt<2><<<dim3(32, 16), 256, 0, stream>>>(h2, w1T, b1, nullptr, gbuf, 4096, 2048, 512);
  if (ws_size >= need4) {
    gemm_skp<<<dim3(32, 4, 4), 256, 0, stream>>>(gbuf, w2T, f2p, 4096, 512, 2048, 512);
    final_comb<<<2048, 256, 0, stream>>>(f2p, 4, b2, x2, out);
  } else if (ws_size >= need2) {
    gemm_skp<<<dim3(32, 4, 2), 256, 0, stream>>>(gbuf, w2T, f2p, 4096, 512, 2048, 1024);
    final_comb<<<2048, 256, 0, stream>>>(f2p, 2, b2, x2, out);
  } else {
    gemm_bt<1><<<dim3(32, 4), 256, 0, stream>>>(gbuf, w2T, b2, x2, out, 4096, 512, 2048);
  }
}

// Round 8
// 147.685 us; speedup vs baseline: 1.2749x; 1.0069x over previous
//
#include <hip/hip_runtime.h>
#include <hip/hip_bf16.h>
#include <stdint.h>

typedef __bf16 bf16;
typedef __bf16 bf16x4 __attribute__((ext_vector_type(4)));
typedef __bf16 bf16x8 __attribute__((ext_vector_type(8)));
typedef float  f32x4  __attribute__((ext_vector_type(4)));
typedef float  f32x16 __attribute__((ext_vector_type(16)));

#define MFMA16(A_, B_, C_) __builtin_amdgcn_mfma_f32_16x16x32_bf16((A_), (B_), (C_), 0, 0, 0)
#define MFMA32(A_, B_, C_) __builtin_amdgcn_mfma_f32_32x32x16_bf16((A_), (B_), (C_), 0, 0, 0)

#define QSCALE 0.1803368801111137f  // 0.125 * log2(e), folded into Wq/bq

__device__ __forceinline__ void gload_lds16(const void* g, void* l) {
  __builtin_amdgcn_global_load_lds(
      (const __attribute__((address_space(1))) unsigned int*)g,
      (__attribute__((address_space(3))) unsigned int*)l, 16, 0, 0);
}

__device__ __forceinline__ unsigned pk2(float lo, float hi_) {
  union { bf16 h[2]; unsigned u; } t;
  t.h[0] = (bf16)lo; t.h[1] = (bf16)hi_;
  return t.u;
}

__device__ __forceinline__ float fast_exp2(float x) {
#if __has_builtin(__builtin_amdgcn_exp2f)
  return __builtin_amdgcn_exp2f(x);
#else
  return exp2f(x);
#endif
}

// ---------------------------------------------------------------------------
// prep: all weight transposes (fp32->bf16, out[n][k]=in[k][n]*scale) + bias pack
// ---------------------------------------------------------------------------
__global__ __launch_bounds__(256) void prep(const float* __restrict__ Wq,
                                            const float* __restrict__ Wk,
                                            const float* __restrict__ Wv,
                                            const float* __restrict__ Wo,
                                            const float* __restrict__ W1,
                                            const float* __restrict__ W2,
                                            const float* __restrict__ bq,
                                            const float* __restrict__ bk,
                                            const float* __restrict__ bv,
                                            bf16* __restrict__ wqkvT, bf16* __restrict__ woT,
                                            bf16* __restrict__ w1T, bf16* __restrict__ w2T,
                                            float* __restrict__ bqkv) {
  const int b = blockIdx.x;
  if (b >= 768) {
    int i = (b - 768) * 256 + threadIdx.x;
    if (i < 1536)
      bqkv[i] = (i < 512) ? bq[i] * QSCALE : (i < 1024 ? bk[i - 512] : bv[i - 1024]);
    return;
  }
  const float* in; bf16* outp; int K, N, t; float sc = 1.f;
  if (b < 64)       { in = Wq; outp = wqkvT;              K = 512;  N = 512;  t = b;       sc = QSCALE; }
  else if (b < 128) { in = Wk; outp = wqkvT + 512 * 512;  K = 512;  N = 512;  t = b - 64;  }
  else if (b < 192) { in = Wv; outp = wqkvT + 1024 * 512; K = 512;  N = 512;  t = b - 128; }
  else if (b < 256) { in = Wo; outp = woT;                K = 512;  N = 512;  t = b - 192; }
  else if (b < 512) { in = W1; outp = w1T;                K = 512;  N = 2048; t = b - 256; }
  else              { in = W2; outp = w2T;                K = 2048; N = 512;  t = b - 512; }
  const int tx = K >> 6;
  const int k0 = (t % tx) * 64, n0 = (t / tx) * 64;
  __shared__ bf16 tile[64][72];
  const int tid = threadIdx.x;
#pragma unroll
  for (int s = 0; s < 16; ++s) {
    int j = tid + s * 256;
    int r = j >> 6, c = j & 63;
    tile[r][c] = (bf16)(in[(size_t)(k0 + r) * N + n0 + c] * sc);
  }
  __syncthreads();
#pragma unroll
  for (int s = 0; s < 16; ++s) {
    int j = tid + s * 256;
    int n = j >> 6, k = j & 63;
    outp[(size_t)(n0 + n) * K + k0 + k] = tile[k][n];
  }
}

// ---------------------------------------------------------------------------
// LayerNorm: x fp32 [4096][512] -> out bf16. One wave per row.
// ---------------------------------------------------------------------------
__global__ __launch_bounds__(256) void ln_k(const float* __restrict__ x,
                                            const float* __restrict__ sc,
                                            const float* __restrict__ bi,
                                            bf16* __restrict__ out) {
  const int w = threadIdx.x >> 6, l = threadIdx.x & 63;
  const int row = blockIdx.x * 4 + w;
  const float4* xp = (const float4*)(x + (size_t)row * 512 + l * 8);
  float4 v0 = xp[0], v1 = xp[1];
  float xv[8] = {v0.x, v0.y, v0.z, v0.w, v1.x, v1.y, v1.z, v1.w};
  float s = 0.f, q = 0.f;
#pragma unroll
  for (int j = 0; j < 8; ++j) { s += xv[j]; q += xv[j] * xv[j]; }
#pragma unroll
  for (int m = 1; m < 64; m <<= 1) { s += __shfl_xor(s, m); q += __shfl_xor(q, m); }
  const float mean = s * (1.f / 512.f);
  const float var = q * (1.f / 512.f) - mean * mean;
  const float rstd = rsqrtf(var + 1e-6f);
  const float4* scp = (const float4*)(sc + l * 8);
  const float4* bip = (const float4*)(bi + l * 8);
  float4 s0 = scp[0], s1 = scp[1], b0 = bip[0], b1 = bip[1];
  float sv[8] = {s0.x, s0.y, s0.z, s0.w, s1.x, s1.y, s1.z, s1.w};
  float bv[8] = {b0.x, b0.y, b0.z, b0.w, b1.x, b1.y, b1.z, b1.w};
  bf16x8 ov;
#pragma unroll
  for (int j = 0; j < 8; ++j) ov[j] = (bf16)((xv[j] - mean) * rstd * sv[j] + bv[j]);
  *(bf16x8*)(out + (size_t)row * 512 + l * 8) = ov;
}

// ---------------------------------------------------------------------------
// ln2_comb: x2 = p0+p1+bo+x (fp32), h2 = LN(x2) (bf16)
// ---------------------------------------------------------------------------
__global__ __launch_bounds__(256) void ln2_comb(const float* __restrict__ p0,
                                                const float* __restrict__ p1,
                                                const float* __restrict__ x,
                                                const float* __restrict__ bo,
                                                const float* __restrict__ sc,
                                                const float* __restrict__ bi,
                                                float* __restrict__ x2,
                                                bf16* __restrict__ h2) {
  const int w = threadIdx.x >> 6, l = threadIdx.x & 63;
  const int row = blockIdx.x * 4 + w;
  const size_t base = (size_t)row * 512 + l * 8;
  float xv[8];
#pragma unroll
  for (int j = 0; j < 2; ++j) {
    float4 a = *(const float4*)(p0 + base + j * 4);
    float4 b = *(const float4*)(p1 + base + j * 4);
    float4 c = *(const float4*)(x + base + j * 4);
    float4 d = *(const float4*)(bo + l * 8 + j * 4);
    xv[j * 4 + 0] = a.x + b.x + c.x + d.x;
    xv[j * 4 + 1] = a.y + b.y + c.y + d.y;
    xv[j * 4 + 2] = a.z + b.z + c.z + d.z;
    xv[j * 4 + 3] = a.w + b.w + c.w + d.w;
  }
  *(float4*)(x2 + base) = make_float4(xv[0], xv[1], xv[2], xv[3]);
  *(float4*)(x2 + base + 4) = make_float4(xv[4], xv[5], xv[6], xv[7]);
  float s = 0.f, q = 0.f;
#pragma unroll
  for (int j = 0; j < 8; ++j) { s += xv[j]; q += xv[j] * xv[j]; }
#pragma unroll
  for (int m = 1; m < 64; m <<= 1) { s += __shfl_xor(s, m); q += __shfl_xor(q, m); }
  const float mean = s * (1.f / 512.f);
  const float var = q * (1.f / 512.f) - mean * mean;
  const float rstd = rsqrtf(var + 1e-6f);
  const float4* scp = (const float4*)(sc + l * 8);
  const float4* bip = (const float4*)(bi + l * 8);
  float4 s0 = scp[0], s1 = scp[1], b0 = bip[0], b1 = bip[1];
  float sv[8] = {s0.x, s0.y, s0.z, s0.w, s1.x, s1.y, s1.z, s1.w};
  float bv[8] = {b0.x, b0.y, b0.z, b0.w, b1.x, b1.y, b1.z, b1.w};
  bf16x8 ov;
#pragma unroll
  for (int j = 0; j < 8; ++j) ov[j] = (bf16)((xv[j] - mean) * rstd * sv[j] + bv[j]);
  *(bf16x8*)(h2 + base) = ov;
}

// out = sum(parts) + b2 + x2   (all fp32)
__global__ __launch_bounds__(256) void final_comb(const float* __restrict__ parts, int nsplit,
                                                  const float* __restrict__ b2,
                                                  const float* __restrict__ x2,
                                                  float* __restrict__ outp) {
  const int i4 = blockIdx.x * 256 + threadIdx.x;
  const size_t off = (size_t)i4 * 4;
  float4 acc = *(const float4*)(x2 + off);
  float4 bb = *(const float4*)(b2 + (off & 511));
  acc.x += bb.x; acc.y += bb.y; acc.z += bb.z; acc.w += bb.w;
  for (int z = 0; z < nsplit; ++z) {
    float4 p = *(const float4*)(parts + (size_t)z * 4096 * 512 + off);
    acc.x += p.x; acc.y += p.y; acc.z += p.z; acc.w += p.w;
  }
  *(float4*)(outp + off) = acc;
}

// ---------------------------------------------------------------------------
// GEMM core, BK=64, XOR-swizzled LDS, DOUBLE-BUFFERED (stage kt+1 before
// computing kt; one barrier per iter drains vmcnt -> dbuf safe).
// EPI 1: +bias+res->f32, 2: +bias,gelu->bf16, 3: qkv split-write q2/k2/v2
// ---------------------------------------------------------------------------
template <int EPI>
__global__ __launch_bounds__(256) void gemm_bt(const bf16* __restrict__ A,
                                               const bf16* __restrict__ Bt,
                                               const float* __restrict__ bias,
                                               const float* __restrict__ res,
                                               void* __restrict__ outp,
                                               bf16* __restrict__ k2,
                                               bf16* __restrict__ v2,
                                               int M, int N, int K) {
  __shared__ bf16 a_lds[2][128 * 64];
  __shared__ bf16 b_lds[2][128 * 64];
  const int m0 = blockIdx.x * 128, n0 = blockIdx.y * 128;
  const int tid = threadIdx.x, l = tid & 63, w = tid >> 6;
  const int wm = w >> 1, wn = w & 1;
  const int lc = l & 15, g = l >> 4;
  const int srow = l >> 3;
  const int cs = (l & 7) ^ srow;

  const bf16* ag = A + (size_t)(m0 + w * 8 + srow) * K + cs * 8;
  const bf16* bg = Bt + (size_t)(n0 + w * 8 + srow) * K + cs * 8;
  const size_t rstep = (size_t)32 * K;

#define GSTAGE(B_)                                                       \
  do {                                                                   \
    _Pragma("unroll")                                                    \
    for (int r_ = 0; r_ < 4; ++r_) {                                     \
      gload_lds16(ag + r_ * rstep, (char*)a_lds[B_] + (r_ * 32 + w * 8) * 128); \
      gload_lds16(bg + r_ * rstep, (char*)b_lds[B_] + (r_ * 32 + w * 8) * 128); \
    }                                                                    \
    ag += 64; bg += 64;                                                  \
  } while (0)

  f32x4 acc[4][4] = {};
  const int kiters = K >> 6;
  GSTAGE(0);
  __syncthreads();
  for (int kt = 0; kt < kiters; ++kt) {
    const int cur = kt & 1;
    if (kt + 1 < kiters) GSTAGE(cur ^ 1);
    const bf16* ab = a_lds[cur];
    const bf16* bb2 = b_lds[cur];
#pragma unroll
    for (int kk = 0; kk < 2; ++kk) {
      bf16x8 af[4], bfr[4];
#pragma unroll
      for (int i = 0; i < 4; ++i) {
        const int sw = ((kk * 4 + g) ^ (lc & 7)) * 8;
        af[i]  = *(const bf16x8*)(ab + (wm * 64 + i * 16 + lc) * 64 + sw);
        bfr[i] = *(const bf16x8*)(bb2 + (wn * 64 + i * 16 + lc) * 64 + sw);
      }
#pragma unroll
      for (int mi = 0; mi < 4; ++mi)
#pragma unroll
        for (int ni = 0; ni < 4; ++ni)
          acc[mi][ni] = MFMA16(af[mi], bfr[ni], acc[mi][ni]);
    }
    __syncthreads();
  }
#undef GSTAGE

#pragma unroll
  for (int mi = 0; mi < 4; ++mi)
#pragma unroll
    for (int ni = 0; ni < 4; ++ni) {
      const int col = n0 + wn * 64 + ni * 16 + lc;
      const float bb = bias[col];
#pragma unroll
      for (int i = 0; i < 4; ++i) {
        const int row = m0 + wm * 64 + mi * 16 + g * 4 + i;
        float v = acc[mi][ni][i] + bb;
        if constexpr (EPI == 1) {
          ((float*)outp)[(size_t)row * N + col] = v + res[(size_t)row * N + col];
        } else if constexpr (EPI == 2) {
          float t = -2.3022077697f * (v + 0.044715f * v * v * v);
          float gl = v / (1.f + fast_exp2(t));
          ((bf16*)outp)[(size_t)row * N + col] = (bf16)gl;
        } else {  // EPI 3: QKV split-write (region uniform per block)
          const bf16 bv16 = (bf16)v;
          if (col < 512) {
            ((bf16*)outp)[(size_t)row * 512 + col] = bv16;           // q2
          } else if (col < 1024) {
            const int hd = (col - 512) >> 6, d = col & 63;
            k2[(size_t)hd * 262144 + (size_t)row * 64 + d] = bv16;
          } else {
            const int hd = (col - 1024) >> 6, d = col & 63;
            v2[(size_t)hd * 262144 + (size_t)(row >> 5) * 2048 + d * 32 + (row & 31)] = bv16;
          }
        }
      }
    }
}

// ---------------------------------------------------------------------------
// Split-K GEMM partial (BK=64, swizzled, double-buffered): parts[kz][M][N] f32
// ---------------------------------------------------------------------------
__global__ __launch_bounds__(256) void gemm_skp(const bf16* __restrict__ A,
                                                const bf16* __restrict__ Bt,
                                                float* __restrict__ parts,
                                                int M, int N, int Kstride, int Kc) {
  __shared__ bf16 a_lds[2][128 * 64];
  __shared__ bf16 b_lds[2][128 * 64];
  const int m0 = blockIdx.x * 128, n0 = blockIdx.y * 128, kz = blockIdx.z;
  A += (size_t)kz * Kc;
  Bt += (size_t)kz * Kc;
  float* outp = parts + (size_t)kz * M * N;
  const int tid = threadIdx.x, l = tid & 63, w = tid >> 6;
  const int wm = w >> 1, wn = w & 1;
  const int lc = l & 15, g = l >> 4;
  const int srow = l >> 3;
  const int cs = (l & 7) ^ srow;

  const bf16* ag = A + (size_t)(m0 + w * 8 + srow) * Kstride + cs * 8;
  const bf16* bg = Bt + (size_t)(n0 + w * 8 + srow) * Kstride + cs * 8;
  const size_t rstep = (size_t)32 * Kstride;

#define GSTAGE(B_)                                                       \
  do {                                                                   \
    _Pragma("unroll")                                                    \
    for (int r_ = 0; r_ < 4; ++r_) {                                     \
      gload_lds16(ag + r_ * rstep, (char*)a_lds[B_] + (r_ * 32 + w * 8) * 128); \
      gload_lds16(bg + r_ * rstep, (char*)b_lds[B_] + (r_ * 32 + w * 8) * 128); \
    }                                                                    \
    ag += 64; bg += 64;                                                  \
  } while (0)

  f32x4 acc[4][4] = {};
  const int kiters = Kc >> 6;
  GSTAGE(0);
  __syncthreads();
  for (int kt = 0; kt < kiters; ++kt) {
    const int cur = kt & 1;
    if (kt + 1 < kiters) GSTAGE(cur ^ 1);
    const bf16* ab = a_lds[cur];
    const bf16* bb2 = b_lds[cur];
#pragma unroll
    for (int kk = 0; kk < 2; ++kk) {
      bf16x8 af[4], bfr[4];
#pragma unroll
      for (int i = 0; i < 4; ++i) {
        const int sw = ((kk * 4 + g) ^ (lc & 7)) * 8;
        af[i]  = *(const bf16x8*)(ab + (wm * 64 + i * 16 + lc) * 64 + sw);
        bfr[i] = *(const bf16x8*)(bb2 + (wn * 64 + i * 16 + lc) * 64 + sw);
      }
#pragma unroll
      for (int mi = 0; mi < 4; ++mi)
#pragma unroll
        for (int ni = 0; ni < 4; ++ni)
          acc[mi][ni] = MFMA16(af[mi], bfr[ni], acc[mi][ni]);
    }
    __syncthreads();
  }
#undef GSTAGE

#pragma unroll
  for (int mi = 0; mi < 4; ++mi)
#pragma unroll
    for (int ni = 0; ni < 4; ++ni) {
      const int col = n0 + wn * 64 + ni * 16 + lc;
#pragma unroll
      for (int i = 0; i < 4; ++i) {
        const int row = m0 + wm * 64 + mi * 16 + g * 4 + i;
        outp[(size_t)row * N + col] = acc[mi][ni][i];
      }
    }
}

// ---------------------------------------------------------------------------
// Flash attention v7 (unchanged structure): block-shared LDS staging, dbuf,
// one barrier/tile; constant-max in-register softmax; raw v_exp2; permlane
// pack. Q from dense q2. Raw O/l partials; attn_comb divides (exact).
// ---------------------------------------------------------------------------
__global__ __launch_bounds__(256, 4) void attn_k(const bf16* __restrict__ q2,
                                                 const bf16* __restrict__ k2,
                                                 const bf16* __restrict__ v2,
                                                 bf16* __restrict__ opart,
                                                 float* __restrict__ lpart) {
  const int bid = blockIdx.x;
  const int head = bid & 7;          // one head per XCD (L2 locality)
  const int qt = (bid >> 3) & 63;
  const int ks = bid >> 9;
  const int w = threadIdx.x >> 6, l = threadIdx.x & 63;
  const int hi = l >> 5, l5 = l & 31;
  const int pair = w >> 1, wq = w & 1;

  __shared__ __align__(16) char smem[32768];
  char* kt_l = smem + pair * 16384;   // [2][4096] B
  char* vt_l = kt_l + 8192;           // [2][4096] B

  const int qrow0 = qt * 64 + wq * 32;
  const bf16* qb = q2 + (size_t)(qrow0 + l5) * 512 + head * 64;
  bf16x8 qf[4];
#pragma unroll
  for (int cc = 0; cc < 4; ++cc) qf[cc] = *(const bf16x8*)(qb + cc * 16 + hi * 8);

  const int kstart = ks * 2048 + pair * 1024;

  const int lr = l >> 3;
  const int lc3 = (l & 7) ^ lr;
  const char* kg = (const char*)k2 + (size_t)head * 524288 + (size_t)kstart * 128 +
                   (wq * 16 + lr) * 128 + lc3 * 16;
  const char* vg = (const char*)v2 + (size_t)head * 524288 + (size_t)(kstart >> 5) * 4096 +
                   (lc3 >> 2) * 2048 + (wq * 16 + lr) * 64 + (lc3 & 3) * 16;
  const int kdst = wq * 2048;

#define STAGE(B_)                                                            \
  do {                                                                       \
    gload_lds16(kg,        kt_l + (B_) * 4096 + kdst);                       \
    gload_lds16(kg + 1024, kt_l + (B_) * 4096 + kdst + 1024);                \
    gload_lds16(vg,        vt_l + (B_) * 4096 + kdst);                       \
    gload_lds16(vg + 512,  vt_l + (B_) * 4096 + kdst + 1024);                \
    kg += 4096; vg += 4096;                                                  \
  } while (0)

  STAGE(0);
  __syncthreads();

  f32x16 o0 = {}, o1 = {};
  float psum = 0.f;
  const int swl = l5 & 7;
  const char* kbase = kt_l + l5 * 128;
  const char* vbase = vt_l + l5 * 128;

  for (int t = 0; t < 32; ++t) {
    const int cur = t & 1;
    if (t < 31) STAGE(cur ^ 1);

    __builtin_amdgcn_s_setprio(1);
    f32x16 s = {};
#pragma unroll
    for (int cc = 0; cc < 4; ++cc) {
      bf16x8 kf = *(const bf16x8*)(kbase + cur * 4096 + ((cc * 2 + hi) ^ swl) * 16);
      s = MFMA32(kf, qf[cc], s);
    }
    __builtin_amdgcn_s_setprio(0);

#pragma unroll
    for (int c = 0; c < 2; ++c) {
      float p[8];
#pragma unroll
      for (int j = 0; j < 8; ++j) p[j] = fast_exp2(s[c * 8 + j]);
      psum += ((p[0] + p[1]) + (p[2] + p[3])) + ((p[4] + p[5]) + (p[6] + p[7]));
      unsigned X = pk2(p[0], p[1]), X2 = pk2(p[2], p[3]);
      unsigned Y = pk2(p[4], p[5]), Y2 = pk2(p[6], p[7]);
      asm volatile("v_permlane32_swap_b32 %0, %1" : "+v"(X), "+v"(Y));
      asm volatile("v_permlane32_swap_b32 %0, %1" : "+v"(X2), "+v"(Y2));
      union { unsigned wd[4]; bf16x8 v; } pa;
      pa.wd[0] = X; pa.wd[1] = X2; pa.wd[2] = Y; pa.wd[3] = Y2;
      bf16x8 vf0 = *(const bf16x8*)(vbase + cur * 4096 + ((c * 2 + hi) ^ swl) * 16);
      bf16x8 vf1 = *(const bf16x8*)(vbase + cur * 4096 + ((4 + c * 2 + hi) ^ swl) * 16);
      __builtin_amdgcn_s_setprio(1);
      o0 = MFMA32(vf0, pa.v, o0);
      o1 = MFMA32(vf1, pa.v, o1);
      __builtin_amdgcn_s_setprio(0);
    }
    __syncthreads();
  }
#undef STAGE

  float* comb = (float*)smem;
  if (w >= 2) {
    float* cb = comb + ((w - 2) * 64 + l) * 33;
#pragma unroll
    for (int r = 0; r < 16; ++r) { cb[r] = o0[r]; cb[16 + r] = o1[r]; }
    cb[32] = psum;
  }
  __syncthreads();
  if (w < 2) {
    const float* cb = comb + (w * 64 + l) * 33;
#pragma unroll
    for (int r = 0; r < 16; ++r) { o0[r] += cb[r]; o1[r] += cb[16 + r]; }
    psum += cb[32];
    const float lsum = psum + __shfl_xor(psum, 32);
    bf16* ob = opart + (size_t)ks * 4096 * 512 + (size_t)(qrow0 + l5) * 512 + head * 64;
#pragma unroll
    for (int dt = 0; dt < 2; ++dt)
#pragma unroll
      for (int rg = 0; rg < 4; ++rg) {
        bf16x4 vv;
#pragma unroll
        for (int e = 0; e < 4; ++e) {
          const float ov = (dt == 0) ? o0[rg * 4 + e] : o1[rg * 4 + e];
          vv[e] = (bf16)ov;
        }
        *(bf16x4*)(ob + dt * 32 + rg * 8 + hi * 4) = vv;
      }
    if (hi == 0) lpart[(ks * 8 + head) * 4096 + qrow0 + l5] = lsum;
  }
}

// attnb[t][col] = (op0+op1)/(l0+l1)
__global__ __launch_bounds__(256) void attn_comb(const bf16* __restrict__ op,
                                                 const float* __restrict__ lp,
                                                 bf16* __restrict__ ob) {
  const int idx = blockIdx.x * 256 + threadIdx.x;   // 262144 = 4096 * 64
  const int t = idx >> 6, c8 = idx & 63;
  const int head = c8 >> 3;
  const size_t o = (size_t)t * 512 + c8 * 8;
  bf16x8 a = *(const bf16x8*)(op + o);
  bf16x8 b = *(const bf16x8*)(op + 2097152 + o);
  const float inv = 1.f / (lp[head * 4096 + t] + lp[32768 + head * 4096 + t]);
  bf16x8 r;
#pragma unroll
  for (int j = 0; j < 8; ++j) r[j] = (bf16)(((float)a[j] + (float)b[j]) * inv);
  *(bf16x8*)(ob + o) = r;
}

// ---------------------------------------------------------------------------
extern "C" void kernel_launch(void* const* d_in, const int* in_sizes, int n_in,
                              void* d_out, int out_size, void* d_ws, size_t ws_size,
                              hipStream_t stream) {
  const float* x    = (const float*)d_in[0];
  const float* ln1s = (const float*)d_in[1];
  const float* ln1b = (const float*)d_in[2];
  const float* Wq   = (const float*)d_in[3];
  const float* bq   = (const float*)d_in[4];
  const float* Wk   = (const float*)d_in[5];
  const float* bk   = (const float*)d_in[6];
  const float* Wv   = (const float*)d_in[7];
  const float* bv   = (const float*)d_in[8];
  const float* Wo   = (const float*)d_in[9];
  const float* bo   = (const float*)d_in[10];
  const float* ln2s = (const float*)d_in[11];
  const float* ln2b = (const float*)d_in[12];
  const float* W1   = (const float*)d_in[13];
  const float* b1   = (const float*)d_in[14];
  const float* W2   = (const float*)d_in[15];
  const float* b2   = (const float*)d_in[16];
  float* out = (float*)d_out;

  char* ws = (char*)d_ws;
  bf16*  wqkvT = (bf16*)(ws + 0);          // [1536][512] 1.5M
  bf16*  woT   = (bf16*)(ws + 1572864);    // [512][512]  0.5M
  bf16*  w1T   = (bf16*)(ws + 2097152);    // [2048][512] 2M
  bf16*  w2T   = (bf16*)(ws + 4194304);    // [512][2048] 2M
  float* bqkv  = (float*)(ws + 6291456);   // 6KB -> 6299648
  float* lpart = (float*)(ws + 6299648);   // 256K -> 6561792
  bf16*  opart = (bf16*)(ws + 6561792);    // [2][4096][512] bf16 8M -> 14950400
  float* x2    = (float*)(ws + 6561792);   // overlays opart (disjoint lifetime)
  bf16*  h     = (bf16*)(ws + 14950400);   // 4M -> 19144704 (h / attnb / h2)
  bf16*  q2    = (bf16*)(ws + 19144704);   // [4096][512] 4M -> 23339008
  bf16*  k2    = (bf16*)(ws + 23339008);   // [8][4096][64] 4M -> 27533312
  bf16*  v2    = (bf16*)(ws + 27533312);   // [8][128][64][32] 4M -> 31727616
  bf16*  attnb = h;
  bf16*  h2    = h;
  float* wop   = (float*)(ws + 19144704);  // 2x8M f32 over dead q2/k2/v2 -> 35921920
  bf16*  gbuf  = (bf16*)(ws + 19144704);   // ffn1 out 16M over dead wop
  float* f2p   = (float*)(ws + 35921920);  // gated
  const size_t need4 = 35921920 + 4ull * 8388608;
  const size_t need2 = 35921920 + 2ull * 8388608;

  prep<<<774, 256, 0, stream>>>(Wq, Wk, Wv, Wo, W1, W2, bq, bk, bv,
                                wqkvT, woT, w1T, w2T, bqkv);

  ln_k<<<1024, 256, 0, stream>>>(x, ln1s, ln1b, h);
  gemm_bt<3><<<dim3(32, 12), 256, 0, stream>>>(h, wqkvT, bqkv, nullptr, q2, k2, v2,
                                               4096, 1536, 512);
  attn_k<<<1024, 256, 0, stream>>>(q2, k2, v2, opart, lpart);
  attn_comb<<<1024, 256, 0, stream>>>(opart, lpart, attnb);
  gemm_skp<<<dim3(32, 4, 2), 256, 0, stream>>>(attnb, woT, wop, 4096, 512, 512, 256);
  ln2_comb<<<1024, 256, 0, stream>>>(wop, wop + 4096 * 512, x, bo, ln2s, ln2b, x2, h2);
  gemm_bt<2><<<dim3(32, 16), 256, 0, stream>>>(h2, w1T, b1, nullptr, gbuf, nullptr, nullptr,
                                               4096, 2048, 512);
  if (ws_size >= need4) {
    gemm_skp<<<dim3(32, 4, 4), 256, 0, stream>>>(gbuf, w2T, f2p, 4096, 512, 2048, 512);
    final_comb<<<2048, 256, 0, stream>>>(f2p, 4, b2, x2, out);
  } else if (ws_size >= need2) {
    gemm_skp<<<dim3(32, 4, 2), 256, 0, stream>>>(gbuf, w2T, f2p, 4096, 512, 2048, 1024);
    final_comb<<<2048, 256, 0, stream>>>(f2p, 2, b2, x2, out);
  } else {
    gemm_bt<1><<<dim3(32, 4), 256, 0, stream>>>(gbuf, w2T, b2, x2, out, nullptr, nullptr,
                                                4096, 512, 2048);
  }
}